// Round 5
// baseline (1468.664 us; speedup 1.0000x reference)
//
#include <hip/hip_runtime.h>
#include <math.h>

#define DEV __device__ __forceinline__

typedef short short8 __attribute__((ext_vector_type(8)));
typedef float float4v __attribute__((ext_vector_type(4)));

// round-to-nearest-even fp32 -> bf16 (values here are finite; no NaN path)
DEV unsigned short f2bf(float f) {
    union { float f; unsigned u; } v; v.f = f;
    unsigned r = v.u + 0x7FFFu + ((v.u >> 16) & 1u);
    return (unsigned short)(r >> 16);
}

// block-wide reduction (256 threads). mode 0 = sum, 1 = max.
DEV float block_reduce(float v, int mode) {
    #pragma unroll
    for (int off = 32; off; off >>= 1) {
        float o = __shfl_xor(v, off);
        v = mode ? fmaxf(v, o) : (v + o);
    }
    __shared__ float sbuf[4];
    __syncthreads();
    if ((threadIdx.x & 63) == 0) sbuf[threadIdx.x >> 6] = v;
    __syncthreads();
    float r = sbuf[0];
    #pragma unroll
    for (int w = 1; w < 4; w++) r = mode ? fmaxf(r, sbuf[w]) : (r + sbuf[w]);
    return r;
}

// ---------------------------------------------------------------------------
// bf16 MFMA GEMM: C[M,N] = A[M,K] @ Bt[N,K]^T (+bias)(+=Cf)(GELU)
// 128x128 tile, BK=32, 256 thr = 4 waves (2x2 of 64x64), 4x4 MFMA tiles/wave.
// Cf written at pitch N; Cb written at pitch cbp (for concat-buffer targets).
// ---------------------------------------------------------------------------
template <bool BIAS, bool ACCUM, bool GELU>
__global__ __launch_bounds__(256) void gemm_bf16_kernel(
    const unsigned short* __restrict__ A, int lda,
    const unsigned short* __restrict__ Bt, int ldb,
    const float* __restrict__ bias,
    float* __restrict__ Cf, unsigned short* __restrict__ Cb, int cbp,
    int N, int K)
{
    __shared__ unsigned short As[128 * 40];   // [row][k] pitch 40 (pad 8)
    __shared__ unsigned short Bs[128 * 40];   // [n-row][k]
    const int tid = threadIdx.x;
    const int w = tid >> 6, lane = tid & 63;
    const int l15 = lane & 15, quad = lane >> 4;
    const int m0 = blockIdx.y * 128, n0 = blockIdx.x * 128;
    const int wm = (w >> 1) * 64, wn = (w & 1) * 64;

    float4v acc[4][4];
    #pragma unroll
    for (int i = 0; i < 4; i++)
        #pragma unroll
        for (int j = 0; j < 4; j++) acc[i][j] = (float4v){0.f, 0.f, 0.f, 0.f};

    for (int k0 = 0; k0 < K; k0 += 32) {
        __syncthreads();
        #pragma unroll
        for (int i = 0; i < 2; i++) {
            const int c = tid + i * 256;          // 512 chunks of 16B
            const int row = c >> 2, kc = (c & 3) * 8;
            *(uint4*)(As + row * 40 + kc) =
                *(const uint4*)(A + (size_t)(m0 + row) * lda + k0 + kc);
            *(uint4*)(Bs + row * 40 + kc) =
                *(const uint4*)(Bt + (size_t)(n0 + row) * ldb + k0 + kc);
        }
        __syncthreads();
        short8 Af[4], Bf[4];
        #pragma unroll
        for (int mt = 0; mt < 4; mt++)
            Af[mt] = *(const short8*)(As + (wm + mt * 16 + l15) * 40 + quad * 8);
        #pragma unroll
        for (int nt = 0; nt < 4; nt++)
            Bf[nt] = *(const short8*)(Bs + (wn + nt * 16 + l15) * 40 + quad * 8);
        #pragma unroll
        for (int mt = 0; mt < 4; mt++)
            #pragma unroll
            for (int nt = 0; nt < 4; nt++)
                acc[mt][nt] = __builtin_amdgcn_mfma_f32_16x16x32_bf16(
                    Af[mt], Bf[nt], acc[mt][nt], 0, 0, 0);
    }

    #pragma unroll
    for (int nt = 0; nt < 4; nt++) {
        const int n = n0 + wn + nt * 16 + l15;
        const float bv = BIAS ? bias[n] : 0.f;
        #pragma unroll
        for (int mt = 0; mt < 4; mt++) {
            #pragma unroll
            for (int r = 0; r < 4; r++) {
                const int m = m0 + wm + mt * 16 + quad * 4 + r;
                const size_t off = (size_t)m * N + n;
                float v = acc[mt][nt][r] + bv;
                if (ACCUM) v += Cf[off];
                if (GELU) v = 0.5f * v * (1.f + erff(v * 0.70710678118654752f));
                if (Cf) Cf[off] = v;
                if (Cb) Cb[(size_t)m * cbp + n] = f2bf(v);
            }
        }
    }
}

// ---------------------------------------------------------------------------
// Batched weight transpose+cast: all W fp32 [K][N] -> Wt bf16 [N][K] in one
// launch. Descriptor table passed by value; blockIdx.x -> (segment, tile).
// ---------------------------------------------------------------------------
struct WtDesc { const float* W; unsigned short* Wt; int K; int N; int base; };
struct WtTable { WtDesc d[14]; };

__global__ __launch_bounds__(256) void wtrans_all_kernel(WtTable tab)
{
    const int bid = blockIdx.x;
    int s = 0;
    #pragma unroll
    for (int i = 1; i < 14; i++) if (bid >= tab.d[i].base) s = i;
    const float* W = tab.d[s].W;
    unsigned short* Wt = tab.d[s].Wt;
    const int K = tab.d[s].K, N = tab.d[s].N;
    const int t = bid - tab.d[s].base;
    const int ntn = N >> 5;
    const int n0 = (t % ntn) * 32, k0 = (t / ntn) * 32;

    __shared__ float tbuf[32][33];
    const int c = threadIdx.x & 31, r8 = threadIdx.x >> 5;
    #pragma unroll
    for (int i = 0; i < 4; i++) {
        const int r = r8 + i * 8;
        tbuf[r][c] = W[(size_t)(k0 + r) * N + n0 + c];
    }
    __syncthreads();
    #pragma unroll
    for (int i = 0; i < 4; i++) {
        const int r = r8 + i * 8;
        Wt[(size_t)(n0 + r) * K + k0 + c] = f2bf(tbuf[c][r]);
    }
}

// bf16 transpose per batch: in [b][R][C] -> out [b][C][R]
__global__ __launch_bounds__(256) void trans_kernel(
    const unsigned short* __restrict__ v, unsigned short* __restrict__ Vt,
    int R, int C)
{
    __shared__ unsigned short t[32][33];
    const int b = blockIdx.z, r0 = blockIdx.x * 32, c0 = blockIdx.y * 32;
    const int c = threadIdx.x & 31, r8 = threadIdx.x >> 5;
    #pragma unroll
    for (int i = 0; i < 4; i++) {
        const int r = r8 + i * 8;
        t[r][c] = v[((size_t)b * R + r0 + r) * C + c0 + c];
    }
    __syncthreads();
    #pragma unroll
    for (int i = 0; i < 4; i++) {
        const int r = r8 + i * 8;
        Vt[((size_t)b * C + c0 + r) * R + r0 + c] = t[c][r];
    }
}

// fp32 -> bf16 elementwise (count = grid*256*4)
__global__ __launch_bounds__(256) void castbf_kernel(
    const float* __restrict__ x, unsigned short* __restrict__ y)
{
    const size_t i = ((size_t)blockIdx.x * 256 + threadIdx.x) * 4;
    float4 v = *(const float4*)(x + i);
    ushort4 o;
    o.x = f2bf(v.x); o.y = f2bf(v.y); o.z = f2bf(v.z); o.w = f2bf(v.w);
    *(ushort4*)(y + i) = o;
}

// ---------------------------------------------------------------------------
// LayerNorm over 1024 cols; optional residuals; fp32 and/or bf16 outputs.
// outb written at row pitch obp (for concat-buffer targets).
// ---------------------------------------------------------------------------
DEV void ln_finish(float4 xv, const float* __restrict__ g,
                   const float* __restrict__ bb, float* __restrict__ outf,
                   unsigned short* __restrict__ outb, size_t basef, size_t baseb)
{
    float s  = xv.x + xv.y + xv.z + xv.w;
    float s2 = xv.x * xv.x + xv.y * xv.y + xv.z * xv.z + xv.w * xv.w;
    #pragma unroll
    for (int off = 32; off; off >>= 1) {
        s += __shfl_xor(s, off);
        s2 += __shfl_xor(s2, off);
    }
    __shared__ float sa[4], sb[4];
    if ((threadIdx.x & 63) == 0) {
        sa[threadIdx.x >> 6] = s; sb[threadIdx.x >> 6] = s2;
    }
    __syncthreads();
    s  = sa[0] + sa[1] + sa[2] + sa[3];
    s2 = sb[0] + sb[1] + sb[2] + sb[3];
    const float mu  = s * (1.f / 1024.f);
    const float var = fmaxf(s2 * (1.f / 1024.f) - mu * mu, 0.f);
    const float inv = rsqrtf(var + 1e-12f);
    const int tid = threadIdx.x;
    float4 gv = ((const float4*)g)[tid];
    float4 bv = ((const float4*)bb)[tid];
    float4 o;
    o.x = (xv.x - mu) * inv * gv.x + bv.x;
    o.y = (xv.y - mu) * inv * gv.y + bv.y;
    o.z = (xv.z - mu) * inv * gv.z + bv.z;
    o.w = (xv.w - mu) * inv * gv.w + bv.w;
    if (outf) ((float4*)(outf + basef))[tid] = o;
    if (outb) {
        ushort4 ob;
        ob.x = f2bf(o.x); ob.y = f2bf(o.y); ob.z = f2bf(o.z); ob.w = f2bf(o.w);
        ((ushort4*)(outb + baseb))[tid] = ob;
    }
}

__global__ __launch_bounds__(256) void ln_kernel(
    const float* __restrict__ x, const float* __restrict__ r1,
    const float* __restrict__ r2, const float* __restrict__ g,
    const float* __restrict__ bb, float* __restrict__ outf,
    unsigned short* __restrict__ outb, int obp)
{
    const size_t base = (size_t)blockIdx.x * 1024;
    const int tid = threadIdx.x;
    float4 xv = ((const float4*)(x + base))[tid];
    if (r1) {
        float4 a = ((const float4*)(r1 + base))[tid];
        xv.x += a.x; xv.y += a.y; xv.z += a.z; xv.w += a.w;
    }
    if (r2) {
        float4 a = ((const float4*)(r2 + base))[tid];
        xv.x += a.x; xv.y += a.y; xv.z += a.z; xv.w += a.w;
    }
    ln_finish(xv, g, bb, outf, outb, base, (size_t)blockIdx.x * obp);
}

__global__ __launch_bounds__(256) void gate_ln_kernel(
    const float* __restrict__ gpre, const float* __restrict__ co,
    const float* __restrict__ gn, const float* __restrict__ g,
    const float* __restrict__ bb, float* __restrict__ outf,
    unsigned short* __restrict__ outb)
{
    const size_t base = (size_t)blockIdx.x * 1024;
    const int tid = threadIdx.x;
    float4 gp = ((const float4*)(gpre + base))[tid];
    float4 cv = ((const float4*)(co + base))[tid];
    float4 gv = ((const float4*)(gn + base))[tid];
    float4 xv; float s;
    s = 1.f / (1.f + __expf(-gp.x)); xv.x = s * cv.x + (1.f - s) * gv.x;
    s = 1.f / (1.f + __expf(-gp.y)); xv.y = s * cv.y + (1.f - s) * gv.y;
    s = 1.f / (1.f + __expf(-gp.z)); xv.z = s * cv.z + (1.f - s) * gv.z;
    s = 1.f / (1.f + __expf(-gp.w)); xv.w = s * cv.w + (1.f - s) * gv.w;
    ln_finish(xv, g, bb, outf, outb, base, base);
}

// ---------------------------------------------------------------------------
// MFMA flash attention + inline focal loss, v3: register-prefetch pipeline.
// Per step: barrier -> regs->LDS -> barrier -> issue next tile loads ->
// compute. Fixed-max softmax; one row-sum reduce after the K loop.
// Block = (n-tile of 64, head, b); wave w owns Q rows [w*16, w*16+16).
// ---------------------------------------------------------------------------
__global__ __launch_bounds__(256) void attn_mfma_kernel(
    const unsigned short* __restrict__ qh,  // [B*N,768] bf16
    const unsigned short* __restrict__ kh,  // [B*N,768]
    const unsigned short* __restrict__ q1,  // [B*N,256]
    const unsigned short* __restrict__ k1,  // [B*N,256]
    const unsigned short* __restrict__ Vt,  // [B*1024(d)][1024(m)] bf16
    const float* __restrict__ am,           // [B*N]
    const float* __restrict__ smask,        // [B,3,N,N]
    unsigned short* __restrict__ ctx,       // [B*N,1024] bf16
    float* __restrict__ nump, float* __restrict__ denp)
{
    const int nb = blockIdx.x;              // n0 = nb*64
    const int h  = blockIdx.y;              // 0 = pos head, 1..3 = struct
    const int b  = blockIdx.z;
    const int tid = threadIdx.x;
    const int w = tid >> 6, lane = tid & 63;
    const int l15 = lane & 15, quad = lane >> 4;
    const int n0 = nb * 64;

    __shared__ unsigned short Ks[32 * 264];     // pitch 264 (pad 8)
    __shared__ unsigned short Vs[256 * 40];     // [d][m] pitch 40
    __shared__ unsigned short Ps[4][16 * 40];   // per-wave P tile

    const unsigned short* qsrc; const unsigned short* ksrc; int kpitch, koff;
    if (h == 0) { qsrc = q1; ksrc = k1; kpitch = 256; koff = 0; }
    else        { qsrc = qh; ksrc = kh; kpitch = 768; koff = (h - 1) * 256; }

    // Q fragments directly from global (each lane: 8 contiguous 16B runs)
    short8 Qf[8];
    {
        const unsigned short* qrow =
            qsrc + (size_t)(b * 1024 + n0 + w * 16 + l15) * kpitch + koff;
        #pragma unroll
        for (int kk = 0; kk < 8; kk++)
            Qf[kk] = *(const short8*)(qrow + kk * 32 + quad * 8);
    }

    // prologue: prefetch K/V tile 0 into registers
    uint4 kreg[4], vreg[4];
    #pragma unroll
    for (int i = 0; i < 4; i++) {
        const int c = tid + i * 256;
        kreg[i] = *(const uint4*)(ksrc + (size_t)(b * 1024 + (c >> 5)) * kpitch
                                  + koff + (c & 31) * 8);
        vreg[i] = *(const uint4*)(Vt + (size_t)(b * 1024 + h * 256 + (c >> 2)) * 1024
                                  + (c & 3) * 8);
    }

    float4v O[16];
    #pragma unroll
    for (int i = 0; i < 16; i++) O[i] = (float4v){0.f, 0.f, 0.f, 0.f};
    float lsum[4] = {0.f, 0.f, 0.f, 0.f};
    float flsum = 0.f, dencnt = 0.f;
    const int nrow_base = n0 + w * 16 + quad * 4;  // + r = this lane's rows
    float amn[4];
    #pragma unroll
    for (int r = 0; r < 4; r++) amn[r] = am[b * 1024 + nrow_base + r];
    const float* smbase = (h > 0)
        ? smask + ((size_t)b * 3 + (h - 1)) * 1024 * 1024 : nullptr;

    for (int step = 0; step < 32; step++) {
        const int m0 = step * 32;
        __syncthreads();
        #pragma unroll
        for (int i = 0; i < 4; i++) {
            const int c = tid + i * 256;
            *(uint4*)(Ks + (c >> 5) * 264 + (c & 31) * 8) = kreg[i];
            *(uint4*)(Vs + (c >> 2) * 40 + (c & 3) * 8) = vreg[i];
        }
        __syncthreads();
        if (step < 31) {                         // prefetch next tile
            const int m1 = m0 + 32;
            #pragma unroll
            for (int i = 0; i < 4; i++) {
                const int c = tid + i * 256;
                kreg[i] = *(const uint4*)(ksrc + (size_t)(b * 1024 + m1 + (c >> 5)) * kpitch
                                          + koff + (c & 31) * 8);
                vreg[i] = *(const uint4*)(Vt + (size_t)(b * 1024 + h * 256 + (c >> 2)) * 1024
                                          + m1 + (c & 3) * 8);
            }
        }

        // S = Q K^T (16 x 32 per wave)
        float4v S[2];
        #pragma unroll
        for (int st = 0; st < 2; st++) {
            float4v a = (float4v){0.f, 0.f, 0.f, 0.f};
            #pragma unroll
            for (int kk = 0; kk < 8; kk++) {
                short8 Kf = *(const short8*)(Ks + (st * 16 + l15) * 264 + kk * 32 + quad * 8);
                a = __builtin_amdgcn_mfma_f32_16x16x32_bf16(Qf[kk], Kf, a, 0, 0, 0);
            }
            S[st] = a;
        }

        // masks, focal loss, exp (fixed-max softmax)
        float e[2][4];
        #pragma unroll
        for (int st = 0; st < 2; st++) {
            const int mcol = m0 + st * 16 + l15;
            const float amm = am[b * 1024 + mcol];
            const float am0 = (1.f - amm) * (-10000.f);
            #pragma unroll
            for (int r = 0; r < 4; r++) {
                const float sraw = S[st][r];
                float scv;
                if (h > 0) {
                    const int nrow = nrow_base + r;
                    const float t  = smbase[(size_t)nrow * 1024 + mcol];
                    const float s3 = sraw + am0;
                    const float idxw =
                        ((amn[r] * amm * ((mcol == nrow) ? 0.f : 1.f)) > 0.5f) ? 1.f : 0.f;
                    // shared-transcendental focal loss (exact algebra):
                    const float E = __expf(-fabsf(s3));
                    const float L = __logf(1.f + E);
                    const float R = 1.f / (1.f + E);
                    const float p = (s3 >= 0.f) ? R : E * R;
                    const float sp = fmaxf(s3, 0.f) + L;      // softplus(s3)
                    const float omp = 1.f - p;
                    flsum += idxw * (0.25f * t * omp * omp * (sp - s3)
                                   + 0.75f * (1.f - t) * p * p * sp);
                    dencnt += idxw;
                    scv = sraw * 0.0625f + (1.f - t) * (-10000.f);
                } else {
                    scv = sraw * 0.0625f + am0;
                }
                const float ev = __expf(fminf(scv, 30.f));  // overflow guard
                e[st][r] = ev;
                lsum[r] += ev;
            }
        }

        // P: C-layout -> LDS -> A-layout (per-wave buffer; no barrier needed)
        #pragma unroll
        for (int st = 0; st < 2; st++)
            #pragma unroll
            for (int r = 0; r < 4; r++)
                Ps[w][(quad * 4 + r) * 40 + st * 16 + l15] = f2bf(e[st][r]);
        const short8 Pf = *(const short8*)(&Ps[w][l15 * 40 + quad * 8]);
        #pragma unroll
        for (int dt = 0; dt < 16; dt++) {
            short8 Vf = *(const short8*)(Vs + (dt * 16 + l15) * 40 + quad * 8);
            O[dt] = __builtin_amdgcn_mfma_f32_16x16x32_bf16(Pf, Vf, O[dt], 0, 0, 0);
        }
    }

    // one row-sum reduction across the 16 col-lanes, then write out
    float rinv[4];
    #pragma unroll
    for (int r = 0; r < 4; r++) {
        float s = lsum[r];
        #pragma unroll
        for (int off = 8; off; off >>= 1) s += __shfl_xor(s, off);
        rinv[r] = 1.f / s;
    }
    #pragma unroll
    for (int dt = 0; dt < 16; dt++)
        #pragma unroll
        for (int r = 0; r < 4; r++)
            ctx[(size_t)(b * 1024 + nrow_base + r) * 1024 + h * 256 + dt * 16 + l15]
                = f2bf(O[dt][r] * rinv[r]);

    if (h > 0) {
        const float fb = block_reduce(flsum, 0);
        if (tid == 0) nump[(b * 3 + (h - 1)) * 16 + nb] = fb;
        if (h == 1) {
            const float db = block_reduce(dencnt, 0);
            if (tid == 0) denp[b * 16 + nb] = db;
        }
    }
}

// ---------------------------------------------------------------------------
// MFMA cross attention v3 (register-prefetch pipeline, fixed-max softmax).
// Block = (n-tile of 64, head, b). qk-dim 64, v-dim 256, M = 512 keys.
// ---------------------------------------------------------------------------
__global__ __launch_bounds__(256) void cross_mfma_kernel(
    const unsigned short* __restrict__ cq,   // [B*N, 256] bf16 (4 heads x 64)
    const unsigned short* __restrict__ ck,   // [B*512, 256] bf16
    const unsigned short* __restrict__ cvt,  // [B][1024(d)][512(m)] bf16
    const float* __restrict__ csm,           // [B*1024, 512]
    unsigned short* __restrict__ cctx)       // [B*N, 1024] bf16
{
    const int nb = blockIdx.x;               // 16 tiles of 64 q-rows
    const int h  = blockIdx.y;               // 4 heads
    const int b  = blockIdx.z;
    const int tid = threadIdx.x;
    const int w = tid >> 6, lane = tid & 63;
    const int l15 = lane & 15, quad = lane >> 4;
    const int n0 = nb * 64;

    __shared__ unsigned short Ks[32 * 72];
    __shared__ unsigned short Vs[256 * 40];   // [d][m] pitch 40
    __shared__ unsigned short Ps[4][16 * 40];

    short8 Qf[2];
    {
        const unsigned short* qrow =
            cq + (size_t)(b * 1024 + n0 + w * 16 + l15) * 256 + h * 64;
        #pragma unroll
        for (int kk = 0; kk < 2; kk++)
            Qf[kk] = *(const short8*)(qrow + kk * 32 + quad * 8);
    }

    // prologue: prefetch K/V tile 0
    uint4 kreg, vreg[4];
    kreg = *(const uint4*)(ck + (size_t)(b * 512 + (tid >> 3)) * 256 + h * 64
                           + (tid & 7) * 8);
    #pragma unroll
    for (int i = 0; i < 4; i++) {
        const int c = tid + i * 256;
        vreg[i] = *(const uint4*)(cvt + (size_t)(b * 1024 + h * 256 + (c >> 2)) * 512
                                  + (c & 3) * 8);
    }

    float4v O[16];
    #pragma unroll
    for (int i = 0; i < 16; i++) O[i] = (float4v){0.f, 0.f, 0.f, 0.f};
    float lsum[4] = {0.f, 0.f, 0.f, 0.f};
    const int nrow_base = n0 + w * 16 + quad * 4;

    for (int step = 0; step < 16; step++) {
        const int m0 = step * 32;
        __syncthreads();
        *(uint4*)(Ks + (tid >> 3) * 72 + (tid & 7) * 8) = kreg;
        #pragma unroll
        for (int i = 0; i < 4; i++) {
            const int c = tid + i * 256;
            *(uint4*)(Vs + (c >> 2) * 40 + (c & 3) * 8) = vreg[i];
        }
        __syncthreads();
        if (step < 15) {
            const int m1 = m0 + 32;
            kreg = *(const uint4*)(ck + (size_t)(b * 512 + m1 + (tid >> 3)) * 256
                                   + h * 64 + (tid & 7) * 8);
            #pragma unroll
            for (int i = 0; i < 4; i++) {
                const int c = tid + i * 256;
                vreg[i] = *(const uint4*)(cvt + (size_t)(b * 1024 + h * 256 + (c >> 2)) * 512
                                          + m1 + (c & 3) * 8);
            }
        }

        // S = Q K^T, masked exp
        float e[2][4];
        #pragma unroll
        for (int st = 0; st < 2; st++) {
            float4v a = (float4v){0.f, 0.f, 0.f, 0.f};
            #pragma unroll
            for (int kk = 0; kk < 2; kk++) {
                short8 Kf = *(const short8*)(Ks + (st * 16 + l15) * 72 + kk * 32 + quad * 8);
                a = __builtin_amdgcn_mfma_f32_16x16x32_bf16(Qf[kk], Kf, a, 0, 0, 0);
            }
            const int mcol = m0 + st * 16 + l15;
            #pragma unroll
            for (int r = 0; r < 4; r++) {
                const float msk = csm[(size_t)(b * 1024 + nrow_base + r) * 512 + mcol];
                const float scv = a[r] * 0.125f + (1.f - msk) * (-10000.f);
                const float ev = __expf(fminf(scv, 30.f));
                e[st][r] = ev;
                lsum[r] += ev;
            }
        }

        // P: C-layout -> LDS -> A-layout (per-wave; no barrier)
        #pragma unroll
        for (int st = 0; st < 2; st++)
            #pragma unroll
            for (int r = 0; r < 4; r++)
                Ps[w][(quad * 4 + r) * 40 + st * 16 + l15] = f2bf(e[st][r]);
        const short8 Pf = *(const short8*)(&Ps[w][l15 * 40 + quad * 8]);
        #pragma unroll
        for (int dt = 0; dt < 16; dt++) {
            short8 Vf = *(const short8*)(Vs + (dt * 16 + l15) * 40 + quad * 8);
            O[dt] = __builtin_amdgcn_mfma_f32_16x16x32_bf16(Pf, Vf, O[dt], 0, 0, 0);
        }
    }

    float rinv[4];
    #pragma unroll
    for (int r = 0; r < 4; r++) {
        float s = lsum[r];
        #pragma unroll
        for (int off = 8; off; off >>= 1) s += __shfl_xor(s, off);
        rinv[r] = 1.f / s;
    }
    #pragma unroll
    for (int dt = 0; dt < 16; dt++)
        #pragma unroll
        for (int r = 0; r < 4; r++)
            cctx[(size_t)(b * 1024 + nrow_base + r) * 1024 + h * 256 + dt * 16 + l15]
                = f2bf(O[dt][r] * rinv[r]);
}

// loss = sum(nump[384]) / (3 * sum(denp[128])), deterministic
__global__ __launch_bounds__(256) void loss_reduce_kernel(
    const float* __restrict__ nump, const float* __restrict__ denp,
    float* __restrict__ out)
{
    __shared__ double sn[256], sd[256];
    const int tid = threadIdx.x;
    double ns = 0.0, ds = 0.0;
    for (int i = tid; i < 384; i += 256) ns += (double)nump[i];
    for (int i = tid; i < 128; i += 256) ds += (double)denp[i];
    sn[tid] = ns; sd[tid] = ds;
    __syncthreads();
    for (int off = 128; off; off >>= 1) {
        if (tid < off) { sn[tid] += sn[tid + off]; sd[tid] += sd[tid + off]; }
        __syncthreads();
    }
    if (tid == 0) out[0] = (float)(sn[0] / (3.0 * sd[0]));
}

// ---------------------------------------------------------------------------
extern "C" void kernel_launch(void* const* d_in, const int* in_sizes, int n_in,
                              void* d_out, int out_size, void* d_ws, size_t ws_size,
                              hipStream_t stream)
{
    (void)in_sizes; (void)n_in; (void)out_size; (void)ws_size;
    const float* hs   = (const float*)d_in[0];
    const float* am   = (const float*)d_in[1];
    const float* smask= (const float*)d_in[2];
    const float* sent = (const float*)d_in[3];
    const float* ent  = (const float*)d_in[4];
    const float* csm  = (const float*)d_in[5];
    const float* enc  = (const float*)d_in[6];
    const float* Wq  = (const float*)d_in[8];  const float* bq  = (const float*)d_in[9];
    const float* Wk  = (const float*)d_in[10]; const float* bk  = (const float*)d_in[11];
    const float* Wv  = (const float*)d_in[12]; const float* bv  = (const float*)d_in[13];
    const float* Wq1 = (const float*)d_in[14]; const float* bq1 = (const float*)d_in[15];
    const float* Wk1 = (const float*)d_in[16]; const float* bk1 = (const float*)d_in[17];
    const float* ln_g= (const float*)d_in[18]; const float* ln_b= (const float*)d_in[19];
    const float* gW  = (const float*)d_in[20]; const float* gb  = (const float*)d_in[21];
    const float* gng = (const float*)d_in[22]; const float* gnb = (const float*)d_in[23];
    const float* cWq = (const float*)d_in[24]; const float* cbq = (const float*)d_in[25];
    const float* cWk = (const float*)d_in[26]; const float* cbk = (const float*)d_in[27];
    const float* cWv = (const float*)d_in[28]; const float* cbv = (const float*)d_in[29];
    const float* cWo = (const float*)d_in[30]; const float* cbo = (const float*)d_in[31];
    const float* cWg = (const float*)d_in[32]; const float* cbg = (const float*)d_in[33];
    const float* clg = (const float*)d_in[34]; const float* clb = (const float*)d_in[35];
    const float* oW1 = (const float*)d_in[36]; const float* ob1 = (const float*)d_in[37];
    const float* l1g = (const float*)d_in[38]; const float* l1b = (const float*)d_in[39];
    const float* oW2 = (const float*)d_in[40]; const float* ob2 = (const float*)d_in[41];
    const float* oW3 = (const float*)d_in[42]; const float* ob3 = (const float*)d_in[43];
    const float* l3g = (const float*)d_in[44]; const float* l3b = (const float*)d_in[45];
    float* out = (float*)d_out;

    typedef unsigned short ush;
    char* wsb = (char*)d_ws;
    // ---- weight-transpose arena (bf16), 14,155,776 elements ----
    ush* WT   = (ush*)wsb;
    ush* wqT  = WT;             ush* wkT  = WT + 786432;   ush* wvT  = WT + 1572864;
    ush* wq1T = WT + 2621440;   ush* wk1T = WT + 2883584;  ush* gWT_ = WT + 3145728;
    ush* cWqT = WT + 4194304;   ush* cWkT = WT + 4456448;  ush* cWvT = WT + 4718592;
    ush* cWoT = WT + 5767168;   ush* cWgT = WT + 6815744;  ush* oW1T = WT + 8912896;
    ush* oW2T = WT + 9961472;   ush* oW3T = WT + 12058624;
    // ---- activation slabs (byte offsets; lifetimes reused) ----
    ush*  hs_bf   = (ush*)(wsb + 28311552);
    ush*  enc_bf  = (ush*)(wsb + 45088768);
    ush*  q_bf    = (ush*)(wsb + 53477376);
    ush*  k_bf    = (ush*)(wsb + 66060288);
    ush*  v_bf    = (ush*)(wsb + 78643200);
    ush*  Vt      = (ush*)(wsb + 95420416);
    ush*  h1_bf   = (ush*)(wsb + 112197632);
    ush*  q1_bf   = (ush*)(wsb + 128974848);
    ush*  k1_bf   = (ush*)(wsb + 133169152);
    ush*  ctx_bf  = (ush*)(wsb + 137363456);
    float* nump   = (float*)(wsb + 154140672);
    float* denp   = (float*)(wsb + 154142208);
    float* gnn_f  = (float*)(wsb + 154144768);
    float* gnnout_f = (float*)(wsb + 187699200);
    ush*  concat_b  = (ush*)(wsb + 221253632);    // [8192][2048] bf16 (33.5 MB)
    ush*  cvt       = (ush*)(wsb + 254808064);    // ends 263,196,672
    // reuse (strictly ordered lifetimes):
    ush*  cq_b      = (ush*)(wsb + 53477376);     // over q_bf
    ush*  ck_b      = (ush*)(wsb + 66060288);     // over k_bf
    ush*  cv_b      = (ush*)(wsb + 78643200);     // over v_bf
    ush*  cctx_b    = (ush*)(wsb + 95420416);     // over Vt
    float* cctxo_f  = (float*)(wsb + 154144768);  // over gnn_f
    float* gatepre_f= (float*)(wsb + 112197632);  // over h1/q1/k1/ctx
    ush*  crossout_b= (ush*)(wsb + 221253632);    // over concat_b (dead after gate)
    float* t_f      = (float*)(wsb + 154144768);  // over cctxo_f
    float* h_f      = (float*)(wsb + 187699200);  // over gnnout_f
    ush*  h_b       = (ush*)(wsb + 28311552);     // over hs_bf
    ush*  h2g_b     = (ush*)(wsb + 45088768);     // over enc/q/k region
    float* h3_f     = (float*)(wsb + 154144768);  // over t_f

    dim3 blk(256);
    // ---- phase 0: casts + batched weight transpose ----
    castbf_kernel<<<8192, blk, 0, stream>>>(hs, hs_bf);
    castbf_kernel<<<4096, blk, 0, stream>>>(enc, enc_bf);
    {
        WtTable tab; int idx = 0, base = 0;
        auto addw = [&](const float* W, ush* Wt, int K, int N) {
            tab.d[idx].W = W; tab.d[idx].Wt = Wt; tab.d[idx].K = K;
            tab.d[idx].N = N; tab.d[idx].base = base;
            base += (K / 32) * (N / 32); idx++;
        };
        addw(Wq,  wqT,  1024, 768);  addw(Wk,  wkT,  1024, 768);
        addw(Wv,  wvT,  1024, 1024); addw(Wq1, wq1T, 1024, 256);
        addw(Wk1, wk1T, 1024, 256);  addw(gW,  gWT_, 1024, 1024);
        addw(cWq, cWqT, 1024, 256);  addw(cWk, cWkT, 1024, 256);
        addw(cWv, cWvT, 1024, 1024); addw(cWo, cWoT, 1024, 1024);
        addw(cWg, cWgT, 2048, 1024); addw(oW1, oW1T, 1024, 1024);
        addw(oW2, oW2T, 1024, 2048); addw(oW3, oW3T, 2048, 1024);
        wtrans_all_kernel<<<base, blk, 0, stream>>>(tab);
    }
    // ---- phase 1: projections ----
    gemm_bf16_kernel<true,false,false><<<dim3(6, 64), blk, 0, stream>>>(
        hs_bf, 1024, wqT, 1024, bq, nullptr, q_bf, 768, 768, 1024);
    gemm_bf16_kernel<true,false,false><<<dim3(6, 64), blk, 0, stream>>>(
        hs_bf, 1024, wkT, 1024, bk, nullptr, k_bf, 768, 768, 1024);
    gemm_bf16_kernel<true,false,false><<<dim3(8, 64), blk, 0, stream>>>(
        hs_bf, 1024, wvT, 1024, bv, nullptr, v_bf, 1024, 1024, 1024);
    ln_kernel<<<8192, blk, 0, stream>>>(hs, sent, ent, ln_g, ln_b, nullptr, h1_bf, 1024);
    gemm_bf16_kernel<true,false,false><<<dim3(2, 64), blk, 0, stream>>>(
        h1_bf, 1024, wq1T, 1024, bq1, nullptr, q1_bf, 256, 256, 1024);
    gemm_bf16_kernel<true,false,false><<<dim3(2, 64), blk, 0, stream>>>(
        h1_bf, 1024, wk1T, 1024, bk1, nullptr, k1_bf, 256, 256, 1024);
    trans_kernel<<<dim3(32, 32, 8), blk, 0, stream>>>(v_bf, Vt, 1024, 1024);
    // ---- phase 2: attention + loss ----
    attn_mfma_kernel<<<dim3(16, 4, 8), blk, 0, stream>>>(
        q_bf, k_bf, q1_bf, k1_bf, Vt, am, smask, ctx_bf, nump, denp);
    loss_reduce_kernel<<<1, blk, 0, stream>>>(nump, denp, out + 8388608);
    // ---- phase 3: gnn (LN writes bf16 into concat left half, pitch 2048) ----
    gemm_bf16_kernel<true,false,false><<<dim3(8, 64), blk, 0, stream>>>(
        ctx_bf, 1024, gWT_, 1024, gb, gnn_f, nullptr, 1024, 1024, 1024);
    ln_kernel<<<8192, blk, 0, stream>>>(gnn_f, nullptr, nullptr, gng, gnb,
                                        gnnout_f, concat_b, 2048);
    // ---- phase 4: cross attention + fused gate ----
    gemm_bf16_kernel<true,false,false><<<dim3(2, 64), blk, 0, stream>>>(
        concat_b, 2048, cWqT, 1024, cbq, nullptr, cq_b, 256, 256, 1024);
    gemm_bf16_kernel<true,false,false><<<dim3(2, 32), blk, 0, stream>>>(
        enc_bf, 1024, cWkT, 1024, cbk, nullptr, ck_b, 256, 256, 1024);
    gemm_bf16_kernel<true,false,false><<<dim3(8, 32), blk, 0, stream>>>(
        enc_bf, 1024, cWvT, 1024, cbv, nullptr, cv_b, 1024, 1024, 1024);
    trans_kernel<<<dim3(16, 32, 8), blk, 0, stream>>>(cv_b, cvt, 512, 1024);
    cross_mfma_kernel<<<dim3(16, 4, 8), blk, 0, stream>>>(
        cq_b, ck_b, cvt, csm, cctx_b);
    gemm_bf16_kernel<true,false,false><<<dim3(8, 64), blk, 0, stream>>>(
        cctx_b, 1024, cWoT, 1024, cbo, cctxo_f, concat_b + 1024, 2048, 1024, 1024);
    gemm_bf16_kernel<true,false,false><<<dim3(8, 64), blk, 0, stream>>>(
        concat_b, 2048, cWgT, 2048, cbg, gatepre_f, nullptr, 1024, 1024, 2048);
    gate_ln_kernel<<<8192, blk, 0, stream>>>(gatepre_f, cctxo_f, gnnout_f,
                                             clg, clb, nullptr, crossout_b);
    // ---- phase 5: output block ----
    gemm_bf16_kernel<true,false,false><<<dim3(8, 64), blk, 0, stream>>>(
        crossout_b, 1024, oW1T, 1024, ob1, t_f, nullptr, 1024, 1024, 1024);
    ln_kernel<<<8192, blk, 0, stream>>>(t_f, hs, nullptr, l1g, l1b, h_f, h_b, 1024);
    gemm_bf16_kernel<true,false,true><<<dim3(16, 64), blk, 0, stream>>>(
        h_b, 1024, oW2T, 1024, ob2, nullptr, h2g_b, 2048, 2048, 1024);
    gemm_bf16_kernel<true,false,false><<<dim3(8, 64), blk, 0, stream>>>(
        h2g_b, 2048, oW3T, 2048, ob3, h3_f, nullptr, 1024, 1024, 2048);
    ln_kernel<<<8192, blk, 0, stream>>>(h3_f, h_f, nullptr, l3g, l3b, out, nullptr, 1024);
}